// Round 3
// baseline (473.212 us; speedup 1.0000x reference)
//
#include <hip/hip_runtime.h>

#define MDIM 4096
#define KDIM 2048
#define HDIM 2048

using bf16x8  = __attribute__((ext_vector_type(8))) short;           // 8 bf16 = 4 VGPRs
using f32x16  = __attribute__((ext_vector_type(16))) float;          // 32x32 MFMA accumulator
using ushort8 = __attribute__((ext_vector_type(8))) unsigned short;

// ---------- fp32 -> bf16 (RNE) ----------
__device__ __forceinline__ unsigned short f2bf(float f) {
  unsigned u = __float_as_uint(f);
  u += 0x7fffu + ((u >> 16) & 1u);
  return (unsigned short)(u >> 16);
}
__device__ __forceinline__ ushort8 cvt8(float4 a, float4 b) {
  ushort8 o;
  o[0]=f2bf(a.x); o[1]=f2bf(a.y); o[2]=f2bf(a.z); o[3]=f2bf(a.w);
  o[4]=f2bf(b.x); o[5]=f2bf(b.y); o[6]=f2bf(b.z); o[7]=f2bf(b.w);
  return o;
}

// ---------- coalesced tiled conversion via LDS transpose ----------
// Layouts (unchanged from R2; fragment-contiguous 16B chunks):
// xb: [mblk 16][kblk 32][c 2048], c = (s*8+mgrp)*64 + l,
//     row = mgrp*32+(l&31), col = kblk*64 + s*16 + (l>>5)*8
// wb: [hblk 64][kblk 32][c 1024], c = s*256 + gate*64 + l,
//     h = hblk*32+(l&31), col = kblk*64 + s*16 + (l>>5)*8
// Global reads are full-row 256B contiguous; global writes are linear chunks.
// LDS scatter uses XOR-by-s swizzle (2-way residual conflict = free, m136).
__global__ __launch_bounds__(256) void cvt_tiled(
    const float* __restrict__ x,
    const float* __restrict__ w0, const float* __restrict__ w1,
    const float* __restrict__ w2, const float* __restrict__ w3,
    unsigned short* __restrict__ xb, unsigned short* __restrict__ wb)
{
  __shared__ __align__(16) unsigned short lds[16384];   // 32 KB
  const int t = threadIdx.x;
  if (blockIdx.x < 512) {                 // ---- x: 16 mblk x 32 kblk, tile 256x64
    const int mblk = blockIdx.x >> 5, kblk = blockIdx.x & 31;
    const float* src = x + (size_t)mblk * 256 * KDIM + kblk * 64;
#pragma unroll
    for (int i = 0; i < 8; ++i) {
      int p = i * 256 + t;                // 2048 chunks of 8 floats
      int r = p >> 3, j = p & 7;
      const float4* sp = (const float4*)(src + (size_t)r * KDIM + j * 8);
      ushort8 o = cvt8(sp[0], sp[1]);
      int s = j >> 1;
      int c = s * 512 + (r >> 5) * 64 + (r & 31) + 32 * (j & 1);
      int cs = c ^ (s << 1);              // bank swizzle
      *(ushort8*)(lds + cs * 8) = o;
    }
    __syncthreads();
    unsigned short* dst = xb + ((size_t)mblk * 32 + kblk) * 16384;
#pragma unroll
    for (int i = 0; i < 8; ++i) {
      int q = i * 256 + t;
      int qs = q ^ (((q >> 9) & 3) << 1); // same bijection
      *(ushort8*)(dst + q * 8) = *(const ushort8*)(lds + qs * 8);
    }
  } else {                                // ---- W: 64 hblk x 32 kblk, tile 4x32x64
    const int b = blockIdx.x - 512;
    const int hblk = b >> 5, kblk = b & 31;
#pragma unroll
    for (int i = 0; i < 4; ++i) {
      int p = i * 256 + t;                // 1024 chunks
      int gate = p >> 8, rr = (p >> 3) & 31, j = p & 7;
      const float* src = (gate == 0) ? w0 : (gate == 1) ? w1 : (gate == 2) ? w2 : w3;
      const float4* sp = (const float4*)(src + (size_t)(hblk * 32 + rr) * KDIM + kblk * 64 + j * 8);
      ushort8 o = cvt8(sp[0], sp[1]);
      int s = j >> 1;
      int c = s * 256 + gate * 64 + rr + 32 * (j & 1);
      int cs = c ^ (s << 1);
      *(ushort8*)(lds + cs * 8) = o;
    }
    __syncthreads();
    unsigned short* dst = wb + ((size_t)hblk * 32 + kblk) * 8192;
#pragma unroll
    for (int i = 0; i < 4; ++i) {
      int q = i * 256 + t;
      int qs = q ^ (((q >> 8) & 3) << 1);
      *(ushort8*)(dst + q * 8) = *(const ushort8*)(lds + qs * 8);
    }
  }
}

// ---------- fast activations (tolerance 1.19e-2) ----------
__device__ __forceinline__ float fast_sigmoid(float x) {
  return __builtin_amdgcn_rcpf(1.f + __expf(-x));
}
__device__ __forceinline__ float fast_tanh(float x) {
  x = fminf(15.f, fmaxf(-15.f, x));
  float e = __expf(2.f * x);
  return (e - 1.f) * __builtin_amdgcn_rcpf(e + 1.f);
}

// ---------- fused 4-gate GEMM + LSTM epilogue, NO LDS / NO BARRIERS ----------
// All fragments loaded global->VGPR from fragment-contiguous layouts
// (coalesced global_load_dwordx4). Compiler pipelines with fine-grained vmcnt.
// Block 256m x (4g x 32h), 4 waves split m. 32x32x16 MFMA; per wave per kblk:
// 24 frag loads, 32 MFMAs. B slab (16 KB/kblk) reused 4x via L1; A slab
// reused 64x across hblk-blocks via L2.
__global__ __launch_bounds__(256) void lstm_fused(
    const unsigned short* __restrict__ xb,
    const unsigned short* __restrict__ wb,
    const float* __restrict__ b0, const float* __restrict__ b1,
    const float* __restrict__ b2, const float* __restrict__ b3,
    const float* __restrict__ cxp,
    float* __restrict__ out)
{
  const int t    = threadIdx.x;
  const int lane = t & 63;
  const int wave = t >> 6;

  const int m0 = blockIdx.y * 256;
  const int h0 = blockIdx.x * 32;

  f32x16 acc[4][2] = {};   // [gate][mf]

  // A-frag (s, mf) at ap + (s*512 + mf*64)*8 shorts; advance 16384/kblk
  const unsigned short* ap = xb + (size_t)blockIdx.y * (32 * 16384)
                                + ((size_t)wave * 128 + lane) * 8;
  // B-frag (s, g) at bp + (s*4+g)*512 shorts; advance 8192/kblk
  const unsigned short* bp = wb + (size_t)blockIdx.x * (32 * 8192)
                                + (size_t)lane * 8;

  for (int kblk = 0; kblk < 32; ++kblk) {
#pragma unroll
    for (int s = 0; s < 4; ++s) {
      bf16x8 af[2], bfr[4];
      af[0] = *(const bf16x8*)(ap + s * 4096);
      af[1] = *(const bf16x8*)(ap + s * 4096 + 512);
#pragma unroll
      for (int g = 0; g < 4; ++g)
        bfr[g] = *(const bf16x8*)(bp + (s * 4 + g) * 512);
#pragma unroll
      for (int g = 0; g < 4; ++g)
#pragma unroll
        for (int mf = 0; mf < 2; ++mf)
          acc[g][mf] = __builtin_amdgcn_mfma_f32_32x32x16_bf16(
              af[mf], bfr[g], acc[g][mf], 0, 0, 0);
    }
    ap += 16384;
    bp += 8192;
  }

  // ---- epilogue: D col=lane&31 (h), row=(reg&3)+8*(reg>>2)+4*(lane>>5) ----
  const int hcol = h0 + (lane & 31);
  const float bi = b0[hcol], bff = b1[hcol], bgv = b2[hcol], bov = b3[hcol];
  const float c0 = cxp[hcol];
  const int rbase = 4 * (lane >> 5);
#pragma unroll
  for (int mf = 0; mf < 2; ++mf) {
    const int mbase = m0 + (wave * 2 + mf) * 32 + rbase;
#pragma unroll
    for (int rr = 0; rr < 16; ++rr) {
      const int m = mbase + (rr & 3) + 8 * (rr >> 2);
      const float vi = fast_sigmoid(acc[0][mf][rr] + bi);
      const float vf = fast_sigmoid(acc[1][mf][rr] + bff);
      const float vg = fast_tanh  (acc[2][mf][rr] + bgv);
      const float vo = fast_sigmoid(acc[3][mf][rr] + bov);
      const float c  = vf * c0 + vi * vg;
      out[(size_t)m * HDIM + hcol] = vo * fast_tanh(c);
    }
  }
}

extern "C" void kernel_launch(void* const* d_in, const int* in_sizes, int n_in,
                              void* d_out, int out_size, void* d_ws, size_t ws_size,
                              hipStream_t stream) {
  const float* x   = (const float*)d_in[0];
  const float* Wi  = (const float*)d_in[1];
  const float* bi  = (const float*)d_in[2];
  const float* Wf  = (const float*)d_in[3];
  const float* bf_ = (const float*)d_in[4];
  const float* Wg  = (const float*)d_in[5];
  const float* bg  = (const float*)d_in[6];
  const float* Wo  = (const float*)d_in[7];
  const float* bo  = (const float*)d_in[8];
  const float* cx  = (const float*)d_in[9];

  unsigned short* xb = (unsigned short*)d_ws;                 // 16 MB
  unsigned short* wb = xb + (size_t)MDIM * KDIM;              // 32 MB

  cvt_tiled<<<dim3(512 + 2048), 256, 0, stream>>>(x, Wi, Wf, Wg, Wo, xb, wb);

  lstm_fused<<<dim3(HDIM / 32, MDIM / 256), 256, 0, stream>>>(
      xb, wb, bi, bf_, bg, bo, cx, (float*)d_out);
}

// Round 4
// 270.433 us; speedup vs baseline: 1.7498x; 1.7498x over previous
//
#include <hip/hip_runtime.h>

#define MDIM 4096
#define KDIM 2048
#define HDIM 2048

using bf16x8  = __attribute__((ext_vector_type(8))) short;           // 8 bf16 = 4 VGPRs
using f32x16  = __attribute__((ext_vector_type(16))) float;          // 32x32 MFMA accumulator
using ushort8 = __attribute__((ext_vector_type(8))) unsigned short;

// ---------- fp32 -> bf16 (RNE) ----------
__device__ __forceinline__ unsigned short f2bf(float f) {
  unsigned u = __float_as_uint(f);
  u += 0x7fffu + ((u >> 16) & 1u);
  return (unsigned short)(u >> 16);
}
__device__ __forceinline__ ushort8 cvt8(float4 a, float4 b) {
  ushort8 o;
  o[0]=f2bf(a.x); o[1]=f2bf(a.y); o[2]=f2bf(a.z); o[3]=f2bf(a.w);
  o[4]=f2bf(b.x); o[5]=f2bf(b.y); o[6]=f2bf(b.z); o[7]=f2bf(b.w);
  return o;
}

// ---------- coalesced tiled conversion via LDS transpose (unchanged from R3) ----------
// xb: [mblk 16][kblk 32][c 2048], c = (s*8+mgrp)*64 + l,
//     row = mgrp*32+(l&31), col = kblk*64 + s*16 + (l>>5)*8
// wb: [hblk 64][kblk 32][c 1024], c = s*256 + gate*64 + l,
//     h = hblk*32+(l&31), col = kblk*64 + s*16 + (l>>5)*8
__global__ __launch_bounds__(256) void cvt_tiled(
    const float* __restrict__ x,
    const float* __restrict__ w0, const float* __restrict__ w1,
    const float* __restrict__ w2, const float* __restrict__ w3,
    unsigned short* __restrict__ xb, unsigned short* __restrict__ wb)
{
  __shared__ __align__(16) unsigned short lds[16384];   // 32 KB
  const int t = threadIdx.x;
  if (blockIdx.x < 512) {                 // ---- x: 16 mblk x 32 kblk, tile 256x64
    const int mblk = blockIdx.x >> 5, kblk = blockIdx.x & 31;
    const float* src = x + (size_t)mblk * 256 * KDIM + kblk * 64;
#pragma unroll
    for (int i = 0; i < 8; ++i) {
      int p = i * 256 + t;
      int r = p >> 3, j = p & 7;
      const float4* sp = (const float4*)(src + (size_t)r * KDIM + j * 8);
      ushort8 o = cvt8(sp[0], sp[1]);
      int s = j >> 1;
      int c = s * 512 + (r >> 5) * 64 + (r & 31) + 32 * (j & 1);
      int cs = c ^ (s << 1);
      *(ushort8*)(lds + cs * 8) = o;
    }
    __syncthreads();
    unsigned short* dst = xb + ((size_t)mblk * 32 + kblk) * 16384;
#pragma unroll
    for (int i = 0; i < 8; ++i) {
      int q = i * 256 + t;
      int qs = q ^ (((q >> 9) & 3) << 1);
      *(ushort8*)(dst + q * 8) = *(const ushort8*)(lds + qs * 8);
    }
  } else {                                // ---- W: 64 hblk x 32 kblk
    const int b = blockIdx.x - 512;
    const int hblk = b >> 5, kblk = b & 31;
#pragma unroll
    for (int i = 0; i < 4; ++i) {
      int p = i * 256 + t;
      int gate = p >> 8, rr = (p >> 3) & 31, j = p & 7;
      const float* src = (gate == 0) ? w0 : (gate == 1) ? w1 : (gate == 2) ? w2 : w3;
      const float4* sp = (const float4*)(src + (size_t)(hblk * 32 + rr) * KDIM + kblk * 64 + j * 8);
      ushort8 o = cvt8(sp[0], sp[1]);
      int s = j >> 1;
      int c = s * 256 + gate * 64 + rr + 32 * (j & 1);
      int cs = c ^ (s << 1);
      *(ushort8*)(lds + cs * 8) = o;
    }
    __syncthreads();
    unsigned short* dst = wb + ((size_t)hblk * 32 + kblk) * 8192;
#pragma unroll
    for (int i = 0; i < 4; ++i) {
      int q = i * 256 + t;
      int qs = q ^ (((q >> 8) & 3) << 1);
      *(ushort8*)(dst + q * 8) = *(const ushort8*)(lds + qs * 8);
    }
  }
}

// ---------- async global -> LDS (16B per lane) ----------
__device__ __forceinline__ void g2l16(const unsigned short* g, unsigned short* l) {
  __builtin_amdgcn_global_load_lds(
      (const __attribute__((address_space(1))) void*)g,
      (__attribute__((address_space(3))) void*)l, 16, 0, 0);
}

// ---------- fast activations (tolerance 1.19e-2) ----------
__device__ __forceinline__ float fast_sigmoid(float x) {
  return __builtin_amdgcn_rcpf(1.f + __expf(-x));
}
__device__ __forceinline__ float fast_tanh(float x) {
  x = fminf(15.f, fmaxf(-15.f, x));
  float e = __expf(2.f * x);
  return (e - 1.f) * __builtin_amdgcn_rcpf(e + 1.f);
}

// ---------- one pipelined K-step ----------
// Prefetch kblk+1 (A: global->VGPR a_nxt; B: glds -> BsNxt), then compute kblk
// from a_cur + BsCur, then ONE barrier. Loads are in flight across the whole
// compute phase (~2048 cyc/SIMD), so the barrier's vmcnt drain finds them done.
__device__ __forceinline__ void kstep(
    const unsigned short* __restrict__ apn, const unsigned short* __restrict__ bpn,
    unsigned short* BsCur, unsigned short* BsNxt,
    bf16x8 (&a_cur)[8], bf16x8 (&a_nxt)[8],
    f32x16 (&acc)[4][2], int t, int lane)
{
#pragma unroll
  for (int s = 0; s < 4; ++s)
#pragma unroll
    for (int mf = 0; mf < 2; ++mf)
      a_nxt[s * 2 + mf] = *(const bf16x8*)(apn + (s * 512 + mf * 64) * 8);
#pragma unroll
  for (int c = 0; c < 4; ++c)
    g2l16(bpn + (c * 256 + t) * 8, BsNxt + (c * 256 + t) * 8);

#pragma unroll
  for (int s = 0; s < 4; ++s) {
    bf16x8 bfr[4];
#pragma unroll
    for (int g = 0; g < 4; ++g)
      bfr[g] = *(const bf16x8*)(BsCur + ((s * 4 + g) * 64 + lane) * 8);
#pragma unroll
    for (int g = 0; g < 4; ++g)
#pragma unroll
      for (int mf = 0; mf < 2; ++mf)
        acc[g][mf] = __builtin_amdgcn_mfma_f32_32x32x16_bf16(
            a_cur[s * 2 + mf], bfr[g], acc[g][mf], 0, 0, 0);
  }
  __syncthreads();
}

// ---------- fused 4-gate GEMM + LSTM epilogue, single-barrier pipeline ----------
// Block 256m x (4g x 32h), 4 waves split m (wave-exclusive A -> VGPR direct).
// B double-buffered in LDS (2 x 16 KB). Manual unroll-by-2 ping-pongs A regs.
__global__ __launch_bounds__(256, 2) void lstm_fused(
    const unsigned short* __restrict__ xb,
    const unsigned short* __restrict__ wb,
    const float* __restrict__ b0, const float* __restrict__ b1,
    const float* __restrict__ b2, const float* __restrict__ b3,
    const float* __restrict__ cxp,
    float* __restrict__ out)
{
  __shared__ __align__(16) unsigned short Bs[2][8192];   // 32 KB

  const int t    = threadIdx.x;
  const int lane = t & 63;
  const int wave = t >> 6;

  const int m0 = blockIdx.y * 256;
  const int h0 = blockIdx.x * 32;

  f32x16 acc[4][2] = {};   // [gate][mf]

  const unsigned short* ap = xb + (size_t)blockIdx.y * (32 * 16384)
                                + ((size_t)wave * 128 + lane) * 8;
  const unsigned short* bp = wb + (size_t)blockIdx.x * (32 * 8192);

  bf16x8 aA[8], aB[8];
  // ---- prologue: kblk 0 ----
#pragma unroll
  for (int s = 0; s < 4; ++s)
#pragma unroll
    for (int mf = 0; mf < 2; ++mf)
      aA[s * 2 + mf] = *(const bf16x8*)(ap + (s * 512 + mf * 64) * 8);
#pragma unroll
  for (int c = 0; c < 4; ++c)
    g2l16(bp + (c * 256 + t) * 8, Bs[0] + (c * 256 + t) * 8);
  __syncthreads();

  // ---- 16 double-steps = 32 kblks ----
  for (int k2 = 0; k2 < 16; ++k2) {
    // even kblk: compute(aA, Bs[0]); prefetch odd into (aB, Bs[1])
    kstep(ap + 16384, bp + 8192, Bs[0], Bs[1], aA, aB, acc, t, lane);
    ap += 16384; bp += 8192;
    // odd kblk: compute(aB, Bs[1]); prefetch next even into (aA, Bs[0])
    const unsigned short* apn = (k2 == 15) ? ap : ap + 16384;   // clamp: last prefetch dummy
    const unsigned short* bpn = (k2 == 15) ? bp : bp + 8192;
    kstep(apn, bpn, Bs[1], Bs[0], aB, aA, acc, t, lane);
    ap = apn; bp = bpn;
  }

  // ---- epilogue: D col=lane&31 (h), row=(reg&3)+8*(reg>>2)+4*(lane>>5) ----
  const int hcol = h0 + (lane & 31);
  const float bi = b0[hcol], bff = b1[hcol], bgv = b2[hcol], bov = b3[hcol];
  const float c0 = cxp[hcol];
  const int rbase = 4 * (lane >> 5);
#pragma unroll
  for (int mf = 0; mf < 2; ++mf) {
    const int mbase = m0 + (wave * 2 + mf) * 32 + rbase;
#pragma unroll
    for (int rr = 0; rr < 16; ++rr) {
      const int m = mbase + (rr & 3) + 8 * (rr >> 2);
      const float vi = fast_sigmoid(acc[0][mf][rr] + bi);
      const float vf = fast_sigmoid(acc[1][mf][rr] + bff);
      const float vg = fast_tanh  (acc[2][mf][rr] + bgv);
      const float vo = fast_sigmoid(acc[3][mf][rr] + bov);
      const float c  = vf * c0 + vi * vg;
      out[(size_t)m * HDIM + hcol] = vo * fast_tanh(c);
    }
  }
}

extern "C" void kernel_launch(void* const* d_in, const int* in_sizes, int n_in,
                              void* d_out, int out_size, void* d_ws, size_t ws_size,
                              hipStream_t stream) {
  const float* x   = (const float*)d_in[0];
  const float* Wi  = (const float*)d_in[1];
  const float* bi  = (const float*)d_in[2];
  const float* Wf  = (const float*)d_in[3];
  const float* bf_ = (const float*)d_in[4];
  const float* Wg  = (const float*)d_in[5];
  const float* bg  = (const float*)d_in[6];
  const float* Wo  = (const float*)d_in[7];
  const float* bo  = (const float*)d_in[8];
  const float* cx  = (const float*)d_in[9];

  unsigned short* xb = (unsigned short*)d_ws;                 // 16 MB
  unsigned short* wb = xb + (size_t)MDIM * KDIM;              // 32 MB

  cvt_tiled<<<dim3(512 + 2048), 256, 0, stream>>>(x, Wi, Wf, Wg, Wo, xb, wb);

  lstm_fused<<<dim3(HDIM / 32, MDIM / 256), 256, 0, stream>>>(
      xb, wb, bi, bf_, bg, bo, cx, (float*)d_out);
}

// Round 5
// 268.934 us; speedup vs baseline: 1.7596x; 1.0056x over previous
//
#include <hip/hip_runtime.h>

#define MDIM 4096
#define KDIM 2048
#define HDIM 2048

using bf16x8  = __attribute__((ext_vector_type(8))) short;           // 8 bf16 = 4 VGPRs
using f32x16  = __attribute__((ext_vector_type(16))) float;          // 32x32 MFMA accumulator
using ushort8 = __attribute__((ext_vector_type(8))) unsigned short;

// ---------- fp32 -> bf16 (RNE) ----------
__device__ __forceinline__ unsigned short f2bf(float f) {
  unsigned u = __float_as_uint(f);
  u += 0x7fffu + ((u >> 16) & 1u);
  return (unsigned short)(u >> 16);
}
__device__ __forceinline__ ushort8 cvt8(float4 a, float4 b) {
  ushort8 o;
  o[0]=f2bf(a.x); o[1]=f2bf(a.y); o[2]=f2bf(a.z); o[3]=f2bf(a.w);
  o[4]=f2bf(b.x); o[5]=f2bf(b.y); o[6]=f2bf(b.z); o[7]=f2bf(b.w);
  return o;
}

// ---------- coalesced tiled conversion via LDS transpose (unchanged from R4) ----------
// xb: [mblk 16][kblk 32][c 2048], c = (s*8+mgrp)*64 + l,
//     row = mgrp*32+(l&31), col = kblk*64 + s*16 + (l>>5)*8
// wb: [hblk 64][kblk 32][c 1024], c = s*256 + gate*64 + l,
//     h = hblk*32+(l&31), col = kblk*64 + s*16 + (l>>5)*8
__global__ __launch_bounds__(256) void cvt_tiled(
    const float* __restrict__ x,
    const float* __restrict__ w0, const float* __restrict__ w1,
    const float* __restrict__ w2, const float* __restrict__ w3,
    unsigned short* __restrict__ xb, unsigned short* __restrict__ wb)
{
  __shared__ __align__(16) unsigned short lds[16384];   // 32 KB
  const int t = threadIdx.x;
  if (blockIdx.x < 512) {                 // ---- x: 16 mblk x 32 kblk, tile 256x64
    const int mblk = blockIdx.x >> 5, kblk = blockIdx.x & 31;
    const float* src = x + (size_t)mblk * 256 * KDIM + kblk * 64;
#pragma unroll
    for (int i = 0; i < 8; ++i) {
      int p = i * 256 + t;
      int r = p >> 3, j = p & 7;
      const float4* sp = (const float4*)(src + (size_t)r * KDIM + j * 8);
      ushort8 o = cvt8(sp[0], sp[1]);
      int s = j >> 1;
      int c = s * 512 + (r >> 5) * 64 + (r & 31) + 32 * (j & 1);
      int cs = c ^ (s << 1);
      *(ushort8*)(lds + cs * 8) = o;
    }
    __syncthreads();
    unsigned short* dst = xb + ((size_t)mblk * 32 + kblk) * 16384;
#pragma unroll
    for (int i = 0; i < 8; ++i) {
      int q = i * 256 + t;
      int qs = q ^ (((q >> 9) & 3) << 1);
      *(ushort8*)(dst + q * 8) = *(const ushort8*)(lds + qs * 8);
    }
  } else {                                // ---- W: 64 hblk x 32 kblk
    const int b = blockIdx.x - 512;
    const int hblk = b >> 5, kblk = b & 31;
#pragma unroll
    for (int i = 0; i < 4; ++i) {
      int p = i * 256 + t;
      int gate = p >> 8, rr = (p >> 3) & 31, j = p & 7;
      const float* src = (gate == 0) ? w0 : (gate == 1) ? w1 : (gate == 2) ? w2 : w3;
      const float4* sp = (const float4*)(src + (size_t)(hblk * 32 + rr) * KDIM + kblk * 64 + j * 8);
      ushort8 o = cvt8(sp[0], sp[1]);
      int s = j >> 1;
      int c = s * 256 + gate * 64 + rr + 32 * (j & 1);
      int cs = c ^ (s << 1);
      *(ushort8*)(lds + cs * 8) = o;
    }
    __syncthreads();
    unsigned short* dst = wb + ((size_t)hblk * 32 + kblk) * 8192;
#pragma unroll
    for (int i = 0; i < 4; ++i) {
      int q = i * 256 + t;
      int qs = q ^ (((q >> 8) & 3) << 1);
      *(ushort8*)(dst + q * 8) = *(const ushort8*)(lds + qs * 8);
    }
  }
}

// ---------- async global -> LDS (16B per lane) ----------
__device__ __forceinline__ void g2l16(const unsigned short* g, unsigned short* l) {
  __builtin_amdgcn_global_load_lds(
      (const __attribute__((address_space(1))) void*)g,
      (__attribute__((address_space(3))) void*)l, 16, 0, 0);
}

// ---------- fast activations (tolerance 1.19e-2) ----------
__device__ __forceinline__ float fast_sigmoid(float x) {
  return __builtin_amdgcn_rcpf(1.f + __expf(-x));
}
__device__ __forceinline__ float fast_tanh(float x) {
  x = fminf(15.f, fmaxf(-15.f, x));
  float e = __expf(2.f * x);
  return (e - 1.f) * __builtin_amdgcn_rcpf(e + 1.f);
}

// ---------- one pipelined K-step ----------
// PF: issue next-kblk loads (B: glds -> BsNxt first, then A: global->VGPR),
// then a HARD scheduling fence so the compiler cannot sink the loads into or
// below the MFMA block (load latency must overlap the ~2k-cyc compute phase).
// Then compute current kblk from a_cur + BsCur; ONE barrier at the end.
template<bool PF>
__device__ __forceinline__ void kstep(
    const unsigned short* __restrict__ apn, const unsigned short* __restrict__ bpn,
    const unsigned short* BsCur, unsigned short* BsNxt,
    bf16x8 (&a_cur)[8], bf16x8 (&a_nxt)[8],
    f32x16 (&acc)[4][2], int t, int lane)
{
  if (PF) {
#pragma unroll
    for (int c = 0; c < 4; ++c)
      g2l16(bpn + (c * 256 + t) * 8, BsNxt + (c * 256 + t) * 8);
#pragma unroll
    for (int s = 0; s < 4; ++s)
#pragma unroll
      for (int mf = 0; mf < 2; ++mf)
        a_nxt[s * 2 + mf] = *(const bf16x8*)(apn + (s * 512 + mf * 64) * 8);
    __builtin_amdgcn_sched_barrier(0);   // pin: all prefetch issues above this line
  }

#pragma unroll
  for (int s = 0; s < 4; ++s) {
    bf16x8 bfr[4];
#pragma unroll
    for (int g = 0; g < 4; ++g)
      bfr[g] = *(const bf16x8*)(BsCur + ((s * 4 + g) * 64 + lane) * 8);
#pragma unroll
    for (int g = 0; g < 4; ++g)
#pragma unroll
      for (int mf = 0; mf < 2; ++mf)
        acc[g][mf] = __builtin_amdgcn_mfma_f32_32x32x16_bf16(
            a_cur[s * 2 + mf], bfr[g], acc[g][mf], 0, 0, 0);
  }
  __syncthreads();
}

// ---------- fused 4-gate GEMM + LSTM epilogue, single-barrier pipeline ----------
// Block 256m x (4g x 32h), 4 waves split m (wave-exclusive A -> VGPR direct).
// B double-buffered in LDS (2 x 16 KB). Unified-file budget: 104 VGPR + 128
// AGPR = 232/wave -> 2 waves/SIMD structural; feed them via pinned prefetch.
__global__ __launch_bounds__(256, 2) void lstm_fused(
    const unsigned short* __restrict__ xb,
    const unsigned short* __restrict__ wb,
    const float* __restrict__ b0, const float* __restrict__ b1,
    const float* __restrict__ b2, const float* __restrict__ b3,
    const float* __restrict__ cxp,
    float* __restrict__ out)
{
  __shared__ __align__(16) unsigned short Bs[2][8192];   // 32 KB

  const int t    = threadIdx.x;
  const int lane = t & 63;
  const int wave = t >> 6;

  const int m0 = blockIdx.y * 256;
  const int h0 = blockIdx.x * 32;

  f32x16 acc[4][2] = {};   // [gate][mf]

  const unsigned short* ap = xb + (size_t)blockIdx.y * (32 * 16384)
                                + ((size_t)wave * 128 + lane) * 8;
  const unsigned short* bp = wb + (size_t)blockIdx.x * (32 * 8192);

  bf16x8 aA[8], aB[8];
  // ---- prologue: kblk 0 into (aA, Bs[0]) ----
#pragma unroll
  for (int c = 0; c < 4; ++c)
    g2l16(bp + (c * 256 + t) * 8, Bs[0] + (c * 256 + t) * 8);
#pragma unroll
  for (int s = 0; s < 4; ++s)
#pragma unroll
    for (int mf = 0; mf < 2; ++mf)
      aA[s * 2 + mf] = *(const bf16x8*)(ap + (s * 512 + mf * 64) * 8);
  ap += 16384; bp += 8192;          // -> kblk 1
  __syncthreads();

  // ---- 15 double-steps: kblk 0..29 ----
  for (int j = 0; j < 15; ++j) {
    kstep<true>(ap, bp, Bs[0], Bs[1], aA, aB, acc, t, lane);
    ap += 16384; bp += 8192;
    kstep<true>(ap, bp, Bs[1], Bs[0], aB, aA, acc, t, lane);
    ap += 16384; bp += 8192;
  }
  // ---- tail: kblk 30 (prefetch 31), then kblk 31 (no prefetch) ----
  kstep<true >(ap, bp, Bs[0], Bs[1], aA, aB, acc, t, lane);
  kstep<false>(nullptr, nullptr, Bs[1], Bs[0], aB, aA, acc, t, lane);

  // ---- epilogue: D col=lane&31 (h), row=(reg&3)+8*(reg>>2)+4*(lane>>5) ----
  const int hcol = h0 + (lane & 31);
  const float bi = b0[hcol], bff = b1[hcol], bgv = b2[hcol], bov = b3[hcol];
  const float c0 = cxp[hcol];
  const int rbase = 4 * (lane >> 5);
#pragma unroll
  for (int mf = 0; mf < 2; ++mf) {
    const int mbase = m0 + (wave * 2 + mf) * 32 + rbase;
#pragma unroll
    for (int rr = 0; rr < 16; ++rr) {
      const int m = mbase + (rr & 3) + 8 * (rr >> 2);
      const float vi = fast_sigmoid(acc[0][mf][rr] + bi);
      const float vf = fast_sigmoid(acc[1][mf][rr] + bff);
      const float vg = fast_tanh  (acc[2][mf][rr] + bgv);
      const float vo = fast_sigmoid(acc[3][mf][rr] + bov);
      const float c  = vf * c0 + vi * vg;
      out[(size_t)m * HDIM + hcol] = vo * fast_tanh(c);
    }
  }
}

extern "C" void kernel_launch(void* const* d_in, const int* in_sizes, int n_in,
                              void* d_out, int out_size, void* d_ws, size_t ws_size,
                              hipStream_t stream) {
  const float* x   = (const float*)d_in[0];
  const float* Wi  = (const float*)d_in[1];
  const float* bi  = (const float*)d_in[2];
  const float* Wf  = (const float*)d_in[3];
  const float* bf_ = (const float*)d_in[4];
  const float* Wg  = (const float*)d_in[5];
  const float* bg  = (const float*)d_in[6];
  const float* Wo  = (const float*)d_in[7];
  const float* bo  = (const float*)d_in[8];
  const float* cx  = (const float*)d_in[9];

  unsigned short* xb = (unsigned short*)d_ws;                 // 16 MB
  unsigned short* wb = xb + (size_t)MDIM * KDIM;              // 32 MB

  cvt_tiled<<<dim3(512 + 2048), 256, 0, stream>>>(x, Wi, Wf, Wg, Wo, xb, wb);

  lstm_fused<<<dim3(HDIM / 32, MDIM / 256), 256, 0, stream>>>(
      xb, wb, bi, bf_, bg, bo, cx, (float*)d_out);
}